// Round 12
// baseline (412.808 us; speedup 1.0000x reference)
//
#include <hip/hip_runtime.h>

#define N_EVENTS 16384
#define DIM 128
#define NK 9
#define NSEQ 2048
#define TT 147456
#define CHUNK 64
#define NCHUNK_MAX (TT/CHUNK + NK)   // 2313
#define NHBLK 576                    // TT / 256 exactly

typedef __attribute__((ext_vector_type(8))) short bf16x8;
typedef __attribute__((ext_vector_type(4))) float f32x4;
typedef __attribute__((ext_vector_type(4))) int i32x4;
typedef __attribute__((ext_vector_type(2))) int i32x2;

// ---- workspace layout (bytes) ----
#define OFF_EV     0UL                                     // events bf16
#define OFF_WC     (OFF_EV   + (size_t)N_EVENTS*DIM*2)     // [w_ih|w_hh] bf16
#define OFF_SCAT   (OFF_WC   + (size_t)512*256*2)
#define OFF_GATH   (OFF_SCAT + (size_t)NK*DIM*DIM*2)
#define OFF_XS     (OFF_GATH + (size_t)NK*DIM*DIM*2)       // xs bf16; REUSED as o_flat after lstm
#define OFF_HS     (OFF_XS   + (size_t)TT*DIM*2)
#define OFF_KLIST  (OFF_HS   + (size_t)TT*DIM*2)
#define OFF_ECNT   (OFF_KLIST+ (size_t)TT*4)               // (unused after R11)
#define OFF_EOFF   (OFF_ECNT + 16384UL*4)                  // event offsets: 16385
#define OFF_ECNT2  (OFF_EOFF + 16392UL*4)                  // event rank counters
#define OFF_TPOS   (OFF_ECNT2+ 16384UL*4)                  // token -> event-sorted dest: TT
#define OFF_SEQOFF (OFF_TPOS + (size_t)TT*4)
#define OFF_GROUP  (OFF_SEQOFF + (size_t)NSEQ*4)
#define OFF_MISC   (OFF_GROUP  + (size_t)NSEQ*4)
#define OFF_BH     (OFF_MISC   + 256UL)                    // blockhist: 576*9 ints
// misc ints: [0..8]=kcount  [32..40]=koff  [48..57]=choff

__device__ __forceinline__ short f2b(float f) {
    union { float f; unsigned u; } v; v.f = f;
    unsigned r = (v.u + 0x7FFFu + ((v.u >> 16) & 1u)) >> 16;
    return (short)r;
}
__device__ __forceinline__ float asf(unsigned u) {
    union { unsigned u; float f; } v; v.u = u; return v.f;
}
// raw v_rcp_f32 — avoids HIP's ~10-instr IEEE divide (the R8 win)
__device__ __forceinline__ float fsig(float x) {
    return __builtin_amdgcn_rcpf(1.f + __expf(-x));
}
__device__ __forceinline__ float ftanh(float x) {
    return 1.f - 2.f * __builtin_amdgcn_rcpf(__expf(2.f * x) + 1.f);
}

// permlane32_swap selectors (dst<-[a.lo,b.lo], src<-[a.hi,b.hi]):
__device__ __forceinline__ float plo(float a, float b) {
    i32x2 r = __builtin_amdgcn_permlane32_swap(__float_as_int(a), __float_as_int(b),
                                               false, false);
    return __int_as_float(r[0]);
}
__device__ __forceinline__ float phi(float a, float b) {
    i32x2 r = __builtin_amdgcn_permlane32_swap(__float_as_int(a), __float_as_int(b),
                                               false, false);
    return __int_as_float(r[1]);
}

// MFMA with the B operand pinned to AGPR class ("a" constraint).
__device__ __forceinline__ void mfma_vab(f32x4& c, bf16x8 a, bf16x8 b) {
    asm("v_mfma_f32_16x16x32_bf16 %0, %1, %2, %0" : "+v"(c) : "v"(a), "a"(b));
}
#define MFA(c, a, b) mfma_vab(c, a, b);

// Workgroup barrier WITHOUT the vmcnt(0) drain __syncthreads() emits (R7 form).
__device__ __forceinline__ void wg_bar_nodrain() {
    __builtin_amdgcn_sched_barrier(0);
    asm volatile("s_waitcnt lgkmcnt(0)");
    __builtin_amdgcn_s_barrier();
    __builtin_amdgcn_sched_barrier(0);
}

// Fused convert + k-histogram (R11): one boundary fewer, and the event
// histogram moved out entirely (now LDS-local in plan block 2), deleting
// 147K device-scope atomicAdds on 16K hot counters.
__global__ __launch_bounds__(256) void convhist_kernel(
        const float* __restrict__ ev, const float* __restrict__ wih,
        const float* __restrict__ whh, const float* __restrict__ sw,
        const float* __restrict__ gw,
        short* __restrict__ evb, short* __restrict__ wcb,
        short* __restrict__ swb, short* __restrict__ gwb,
        int* __restrict__ ecnt2,
        const int* __restrict__ pos, int* __restrict__ blockhist) {
    __shared__ int h[NK];
    int tid = threadIdx.x;
    int b = blockIdx.x;
    int gidx = b * 256 + tid;                 // 576*256 = TT exactly
    const int GSTRIDE = NHBLK * 256;
    if (tid < NK) h[tid] = 0;
    __syncthreads();
    atomicAdd(&h[pos[gidx]], 1);              // k-hist: one token per thread
    // convert (grid-stride; independent of hist)
    for (int idx = gidx; idx < N_EVENTS * DIM; idx += GSTRIDE) evb[idx] = f2b(ev[idx]);
    for (int idx = gidx; idx < 512 * DIM; idx += GSTRIDE) {
        int j = idx >> 7, d = idx & 127;
        wcb[j * 256 + d]       = f2b(wih[idx]);
        wcb[j * 256 + 128 + d] = f2b(whh[idx]);
    }
    for (int idx = gidx; idx < NK * DIM * DIM; idx += GSTRIDE) {
        swb[idx] = f2b(sw[idx]); gwb[idx] = f2b(gw[idx]);
    }
    for (int idx = gidx; idx < N_EVENTS; idx += GSTRIDE) ecnt2[idx] = 0;
    __syncthreads();
    if (tid < NK) blockhist[b * NK + tid] = h[tid];
}

// 3-role planning kernel: block0 = k-bin scan, block1 = seq setup,
// block2 = event histogram (LDS, 64KB) + scan -> eoff.
__global__ void plan_kernel(int* __restrict__ blockhist, int* __restrict__ misc,
                            const int* __restrict__ lengths, int* __restrict__ seq_off,
                            int* __restrict__ grouped,
                            const int* __restrict__ orig, int* __restrict__ eoff) {
    __shared__ int smem[N_EVENTS + 256];   // 66.5 KB; per-block role overlay
    int tid = threadIdx.x;
    if (blockIdx.x == 0) {
        int* h = smem;                     // NHBLK*NK = 5184 ints
        for (int i = tid; i < NHBLK * NK; i += 256) h[i] = blockhist[i];
        __syncthreads();
        if (tid < NK) {
            int run = 0;
            for (int b = 0; b < NHBLK; b++) {
                int v = h[b * NK + tid];
                h[b * NK + tid] = run;
                run += v;
            }
            misc[tid] = run;
        }
        __syncthreads();
        if (tid == 0) {
            int ko = 0, co = 0;
            for (int k = 0; k < NK; k++) {
                int c = misc[k];
                misc[32 + k] = ko;
                misc[48 + k] = co;
                ko += c;
                co += (c + CHUNK - 1) / CHUNK;
            }
            misc[48 + NK] = co;
        }
        __syncthreads();
        for (int i = tid; i < NHBLK * NK; i += 256) blockhist[i] = h[i];
    } else if (blockIdx.x == 1) {
        int* lens = smem;                  // 2048
        int* tsum = smem + 2048;           // 256
        int* tlong = smem + 2304;          // 256
        for (int i = tid; i < NSEQ; i += 256) lens[i] = lengths[i];
        __syncthreads();
        int base = tid * 8;
        int ls[8]; int s = 0, lc = 0;
        #pragma unroll
        for (int i = 0; i < 8; i++) { ls[i] = lens[base + i]; s += ls[i]; lc += (ls[i] > 64) ? 1 : 0; }
        tsum[tid] = s; tlong[tid] = lc;
        __syncthreads();
        for (int d = 1; d < 256; d <<= 1) {
            int a = (tid >= d) ? tsum[tid - d] : 0;
            int b = (tid >= d) ? tlong[tid - d] : 0;
            __syncthreads();
            tsum[tid] += a; tlong[tid] += b;
            __syncthreads();
        }
        int nlong_total = tlong[255];
        int excl = tsum[tid] - s;
        int excl_long = tlong[tid] - lc;
        int run = 0, runl = 0;
        #pragma unroll
        for (int i = 0; i < 8; i++) {
            int sid = base + i;
            seq_off[sid] = excl + run;
            int lb = excl_long + runl;
            if (ls[i] > 64) { grouped[lb] = sid; runl++; }
            else            { grouped[nlong_total + (sid - lb)] = sid; }
            run += ls[i];
        }
    } else {
        // event histogram in LDS + scan: 16384 bins, 64 per thread
        int* hist = smem;                  // 16384
        int* part = smem + N_EVENTS;       // 256
        for (int i = tid; i < N_EVENTS; i += 256) hist[i] = 0;
        __syncthreads();
        for (int i = tid; i < TT; i += 256) atomicAdd(&hist[orig[i]], 1);
        __syncthreads();
        int base = tid * 64;
        int s = 0;
        for (int j = 0; j < 64; j++) s += hist[base + j];
        part[tid] = s;
        __syncthreads();
        for (int d = 1; d < 256; d <<= 1) {
            int a = (tid >= d) ? part[tid - d] : 0;
            __syncthreads();
            part[tid] += a;
            __syncthreads();
        }
        int run = part[tid] - s;
        for (int j = 0; j < 64; j++) {
            eoff[base + j] = run;
            run += hist[base + j];
        }
        if (tid == 255) eoff[N_EVENTS] = run;
    }
}

// scatter tokens to k-sorted klist (LDS rank) + write each token's
// event-sorted destination tokpos[t] = eoff[orig[t]] + rank (R9 layout:
// mode-1 gemm scatters rows to event order so gather_ln reads contiguously).
__global__ void fill_kernel(const int* __restrict__ pos, const int* __restrict__ orig,
                            const int* __restrict__ blockhist, const int* __restrict__ misc,
                            int* __restrict__ klist,
                            const int* __restrict__ eoff, int* __restrict__ ecnt2,
                            int* __restrict__ tokpos) {
    __shared__ int off[NK];
    int tid = threadIdx.x;
    if (tid < NK) off[tid] = misc[32 + tid] + blockhist[blockIdx.x * NK + tid];
    __syncthreads();
    int t = blockIdx.x * 256 + tid;
    int p = atomicAdd(&off[pos[t]], 1);
    klist[p] = t;
    int o = orig[t];
    int p2 = atomicAdd(&ecnt2[o], 1);
    tokpos[t] = eoff[o] + p2;
}

// bucketed position-projection GEMM (R9 verbatim, measured-best path)
// mode 0: A rows = evb[orig[tok]], out rows -> xs[tok]            (bf16)
// mode 1: A rows = hs[tok],        out rows -> o_flat[tokpos[tok]] (bf16)
__global__ void bucket_gemm(const short* __restrict__ src, const short* __restrict__ wall,
                            const int* __restrict__ klist, const int* __restrict__ misc,
                            const int* __restrict__ orig, const int* __restrict__ tokpos,
                            short* __restrict__ rows_out, int mode) {
    const int* chunkoff = misc + 48;
    int b = blockIdx.x;
    if (b >= chunkoff[NK]) return;
    int k = 0;
    while (k < NK - 1 && chunkoff[k + 1] <= b) k++;
    int lc = b - chunkoff[k];
    int cnt = misc[k];
    int base = misc[32 + k] + lc * CHUNK;
    int nv = min(CHUNK, cnt - lc * CHUNK);

    __shared__ int wpos[CHUNK], ridx[CHUNK];
    __shared__ short A[CHUNK * 136];
    int tid = threadIdx.x;
    if (tid < CHUNK) {
        int tv = klist[base + ((tid < nv) ? tid : 0)];
        ridx[tid] = (mode == 0) ? orig[tv] : tv;
        wpos[tid] = (mode == 0) ? tv : tokpos[tv];
    }
    __syncthreads();
    {
        int row = tid >> 2, part = tid & 3;
        const i32x4* s4 = (const i32x4*)(src + (size_t)ridx[row] * DIM + part * 32);
        i32x4* d4 = (i32x4*)(A + row * 136 + part * 32);
        d4[0] = s4[0]; d4[1] = s4[1]; d4[2] = s4[2]; d4[3] = s4[3];
    }
    __syncthreads();
    int wave = tid >> 6, lane = tid & 63, l15 = lane & 15, q = lane >> 4;
    const short* wk = wall + (size_t)k * DIM * DIM;
    bf16x8 Bf[2][4];
    #pragma unroll
    for (int nt = 0; nt < 2; nt++) {
        int h = wave * 32 + nt * 16 + l15;
        #pragma unroll
        for (int kt = 0; kt < 4; kt++)
            Bf[nt][kt] = *(const bf16x8*)(wk + h * DIM + kt * 32 + q * 8);
    }
    f32x4 C[4][2];
    #pragma unroll
    for (int mt = 0; mt < 4; mt++)
        #pragma unroll
        for (int nt = 0; nt < 2; nt++) C[mt][nt] = (f32x4){0.f, 0.f, 0.f, 0.f};
    #pragma unroll
    for (int mt = 0; mt < 4; mt++) {
        bf16x8 Afr[4];
        const short* ar = A + (mt * 16 + l15) * 136 + q * 8;
        Afr[0] = *(const bf16x8*)(ar);
        Afr[1] = *(const bf16x8*)(ar + 32);
        Afr[2] = *(const bf16x8*)(ar + 64);
        Afr[3] = *(const bf16x8*)(ar + 96);
        #pragma unroll
        for (int nt = 0; nt < 2; nt++)
            #pragma unroll
            for (int kt = 0; kt < 4; kt++)
                C[mt][nt] = __builtin_amdgcn_mfma_f32_16x16x32_bf16(Afr[kt], Bf[nt][kt], C[mt][nt], 0, 0, 0);
    }
    __syncthreads();
    #pragma unroll
    for (int mt = 0; mt < 4; mt++)
        #pragma unroll
        for (int nt = 0; nt < 2; nt++)
            #pragma unroll
            for (int r = 0; r < 4; r++) {
                int row = mt * 16 + q * 4 + r;
                int col = wave * 32 + nt * 16 + l15;
                A[row * 136 + col] = f2b(C[mt][nt][r]);
            }
    __syncthreads();
    {
        int row = tid >> 2, part = tid & 3;
        if (row < nv) {
            const i32x4* s4 = (const i32x4*)(A + row * 136 + part * 32);
            i32x4* d4 = (i32x4*)(rows_out + (size_t)wpos[row] * DIM + part * 32);
            d4[0] = s4[0]; d4[1] = s4[1]; d4[2] = s4[2]; d4[3] = s4[3];
        }
    }
}

// ---- 2-step x-batched LSTM group (R7 structure, 120.5 us measured) ----
#define TAIL(IDX, SEL, SLOT) { \
    float iA = SEL(Ci[0], Ci[2]), iB = SEL(Ci[1], Ci[3]); \
    float fA = SEL(Cf[0], Cf[2]), fB = SEL(Cf[1], Cf[3]); \
    float gA = SEL(Cg[0], Cg[2]), gB = SEL(Cg[1], Cg[3]); \
    float oA = SEL(Co[0], Co[2]), oB = SEL(Co[1], Co[3]); \
    if ((IDX) < lenA) { \
        float si = fsig(iA), sf = fsig(fA), so = fsig(oA); \
        float tg = ftanh(gA); \
        float cn = sf * cA + si * tg; \
        float th = ftanh(cn); \
        cA = cn; \
        hb[(SLOT) * 1088 + rowA * 136 + u] = f2b(so * th); \
    } \
    if ((IDX) < lenB) { \
        float si = fsig(iB), sf = fsig(fB), so = fsig(oB); \
        float tg = ftanh(gB); \
        float cn = sf * cB + si * tg; \
        float th = ftanh(cn); \
        cB = cn; \
        hb[(SLOT) * 1088 + rowB * 136 + u] = f2b(so * th); \
    } \
}

#define LSTM_G(J2, PF) { \
    const int i2 = ib8 + 2 * (J2); \
    f32x4 Ci = {0.f,0.f,0.f,0.f}, Cf = {0.f,0.f,0.f,0.f}; \
    f32x4 Cg = {0.f,0.f,0.f,0.f}, Co = {0.f,0.f,0.f,0.f}; \
    MFA(Ci, PF[0], Bf[0][0]) MFA(Cf, PF[0], Bf[1][0]) \
    MFA(Cg, PF[0], Bf[2][0]) MFA(Co, PF[0], Bf[3][0]) \
    MFA(Ci, PF[1], Bf[0][1]) MFA(Cf, PF[1], Bf[1][1]) \
    MFA(Cg, PF[1], Bf[2][1]) MFA(Co, PF[1], Bf[3][1]) \
    MFA(Ci, PF[2], Bf[0][2]) MFA(Cf, PF[2], Bf[1][2]) \
    MFA(Cg, PF[2], Bf[2][2]) MFA(Co, PF[2], Bf[3][2]) \
    MFA(Ci, PF[3], Bf[0][3]) MFA(Cf, PF[3], Bf[1][3]) \
    MFA(Cg, PF[3], Bf[2][3]) MFA(Co, PF[3], Bf[3][3]) \
    bf16x8 He0, He1, He2, He3; \
    { const short* hp_ = b0 + (lo8 ? (((2*(J2)+7)&7) * 1088) : 8704); \
      He0 = *(const bf16x8*)(hp_);      He1 = *(const bf16x8*)(hp_ + 32); \
      He2 = *(const bf16x8*)(hp_ + 64); He3 = *(const bf16x8*)(hp_ + 96); } \
    MFA(Ci, He0, Bf[0][4]) MFA(Cf, He0, Bf[1][4]) \
    MFA(Cg, He0, Bf[2][4]) MFA(Co, He0, Bf[3][4]) \
    MFA(Ci, He1, Bf[0][5]) MFA(Cf, He1, Bf[1][5]) \
    MFA(Cg, He1, Bf[2][5]) MFA(Co, He1, Bf[3][5]) \
    MFA(Ci, He2, Bf[0][6]) MFA(Cf, He2, Bf[1][6]) \
    MFA(Cg, He2, Bf[2][6]) MFA(Co, He2, Bf[3][6]) \
    MFA(Ci, He3, Bf[0][7]) MFA(Cf, He3, Bf[1][7]) \
    MFA(Cg, He3, Bf[2][7]) MFA(Co, He3, Bf[3][7]) \
    TAIL(i2, plo, (2*(J2)) & 7) \
    wg_bar_nodrain(); \
    bf16x8 Ho0, Ho1, Ho2, Ho3; \
    { const short* hp_ = b0 + (lo8 ? 8704 : (((2*(J2)) & 7) * 1088)); \
      Ho0 = *(const bf16x8*)(hp_);      Ho1 = *(const bf16x8*)(hp_ + 32); \
      Ho2 = *(const bf16x8*)(hp_ + 64); Ho3 = *(const bf16x8*)(hp_ + 96); } \
    MFA(Ci, Ho0, Bf[0][4]) MFA(Cf, Ho0, Bf[1][4]) \
    MFA(Cg, Ho0, Bf[2][4]) MFA(Co, Ho0, Bf[3][4]) \
    MFA(Ci, Ho1, Bf[0][5]) MFA(Cf, Ho1, Bf[1][5]) \
    MFA(Cg, Ho1, Bf[2][5]) MFA(Co, Ho1, Bf[3][5]) \
    MFA(Ci, Ho2, Bf[0][6]) MFA(Cf, Ho2, Bf[1][6]) \
    MFA(Cg, Ho2, Bf[2][6]) MFA(Co, Ho2, Bf[3][6]) \
    MFA(Ci, Ho3, Bf[0][7]) MFA(Cf, Ho3, Bf[1][7]) \
    MFA(Cg, Ho3, Bf[2][7]) MFA(Co, Ho3, Bf[3][7]) \
    { const short* xp_ = xs + xoff; \
      PF[0] = *(const bf16x8*)(xp_);      PF[1] = *(const bf16x8*)(xp_ + 32); \
      PF[2] = *(const bf16x8*)(xp_ + 64); PF[3] = *(const bf16x8*)(xp_ + 96); } \
    xoff += ((i2 + 6 + loff) < my_len) ? 2 * DIM : 0; \
    TAIL(i2 + 1, phi, (2*(J2)+1) & 7) \
    wg_bar_nodrain(); \
}

// Persistent per-sequence LSTM — 2-step x-batched (R7/R9, 120.5 us).
__global__ __launch_bounds__(512)
__attribute__((amdgpu_waves_per_eu(2, 2)))
void lstm_kernel(
        const short* __restrict__ xs, const short* __restrict__ wc,
        short* __restrict__ hstore, const int* __restrict__ seq_off,
        const int* __restrict__ grouped, const int* __restrict__ lengths) {
    __shared__ int s_off[8], s_len[8];
    __shared__ short hchunk[11][8][136];   // slots 0-7 = h ring; slot 8 = always-zero
    int tid = threadIdx.x;
    if (tid < 8) {
        int s = grouped[blockIdx.x * 8 + tid];
        s_off[tid] = seq_off[s];
        s_len[tid] = lengths[s];
    }
    for (int j = tid; j < 11 * 8 * 136; j += 512) ((short*)hchunk)[j] = 0;
    __syncthreads();
    int lane = tid & 63, l15 = lane & 15, ql = lane >> 4;
    int wave = tid >> 6;
    int u = wave * 16 + l15;
    short* hb = (short*)hchunk;
    bf16x8 Bf[4][8];
    #pragma unroll
    for (int g = 0; g < 4; g++) {
        int j = g * 128 + u;
        #pragma unroll
        for (int kt = 0; kt < 8; kt++)
            Bf[g][kt] = *(const bf16x8*)(wc + j * 256 + kt * 32 + ql * 8);
    }
    int maxlen = 0;
    #pragma unroll
    for (int i = 0; i < 8; i++) maxlen = max(maxlen, s_len[i]);
    int sq = l15 & 7;
    int loff = l15 >> 3;             // 0 = even-step row, 1 = odd-step row
    bool lo8 = (l15 < 8);
    int my_off = s_off[sq];
    int my_len = s_len[sq];
    const short* b0 = hb + sq * 136 + ql * 8;   // + slot*1088 selects ring slot
    int rowA = (ql < 2) ? (ql * 4 + 0) : ((ql - 2) * 4 + 2);
    int rowB = (ql < 2) ? (ql * 4 + 1) : ((ql - 2) * 4 + 3);
    int lenA = s_len[rowA], lenB = s_len[rowB];
    float cA = 0.f, cB = 0.f;
    // prime: Pf0 = steps {0,1}, Pf1 = steps {2,3} (all 16 A-rows loaded)
    bf16x8 Pf0[4], Pf1[4];
    int xoff = (my_off + loff) * DIM + ql * 8;
    {
        const short* xp = xs + xoff;
        Pf0[0] = *(const bf16x8*)(xp);      Pf0[1] = *(const bf16x8*)(xp + 32);
        Pf0[2] = *(const bf16x8*)(xp + 64); Pf0[3] = *(const bf16x8*)(xp + 96);
        const short* xq = xp + 2 * DIM;
        Pf1[0] = *(const bf16x8*)(xq);      Pf1[1] = *(const bf16x8*)(xq + 32);
        Pf1[2] = *(const bf16x8*)(xq + 64); Pf1[3] = *(const bf16x8*)(xq + 96);
    }
    xoff += 4 * DIM;   // first refill target = steps {4,5} (valid: len >= 36)

    int nb8 = (maxlen + 7) >> 3;
    for (int ob = 0; ob < nb8; ob++) {
        int ib8 = ob * 8;
        LSTM_G(0, Pf0)
        LSTM_G(1, Pf1)
        LSTM_G(2, Pf0)
        LSTM_G(3, Pf1)
        #pragma unroll
        for (int it = 0; it < 2; it++) {
            int idx = tid + it * 512;
            int st = idx >> 7, s = (idx >> 4) & 7, part = idx & 15;
            int ig = ib8 + st;
            if (ig < s_len[s]) {
                i32x4 v = *(const i32x4*)&hchunk[st][s][part * 8];
                *(i32x4*)(hstore + (size_t)(s_off[s] + ig) * DIM + part * 8) = v;
            }
        }
        wg_bar_nodrain();
    }
}

// gather each event's rows — CONTIGUOUS [eoff[e], eoff[e+1]) (R9 layout).
__global__ void gather_ln(const short* __restrict__ of, const int* __restrict__ eoff,
                          const float* __restrict__ ev,
                          const float* __restrict__ g, const float* __restrict__ bta,
                          float* __restrict__ out) {
    int tid = threadIdx.x;
    int wave = tid >> 6, lane = tid & 63;
    int e = blockIdx.x * 4 + wave;
    int s0 = eoff[e], s1 = eoff[e + 1];
    float x0 = 0.f, x1 = 0.f;
    for (int j = s0; j < s1; j++) {
        unsigned v = *(const unsigned*)(of + (size_t)j * DIM + lane * 2);
        x0 += asf(v << 16);
        x1 += asf(v & 0xffff0000u);
    }
    const float2* e2 = (const float2*)(ev + (size_t)e * DIM);
    float2 evv = e2[lane];
    x0 += evv.x; x1 += evv.y;
    float sm = x0 + x1, sq = x0 * x0 + x1 * x1;
    #pragma unroll
    for (int m = 1; m < 64; m <<= 1) {
        sm += __shfl_xor(sm, m, 64);
        sq += __shfl_xor(sq, m, 64);
    }
    float mean = sm * (1.f / DIM);
    float var = sq * (1.f / DIM) - mean * mean;
    float rs = rsqrtf(var + 1e-5f);
    float2 gv = ((const float2*)g)[lane], bv = ((const float2*)bta)[lane];
    float2 ov;
    ov.x = (x0 - mean) * rs * gv.x + bv.x;
    ov.y = (x1 - mean) * rs * gv.y + bv.y;
    ((float2*)(out + (size_t)e * DIM))[lane] = ov;
}

extern "C" void kernel_launch(void* const* d_in, const int* in_sizes, int n_in,
                              void* d_out, int out_size, void* d_ws, size_t ws_size,
                              hipStream_t stream) {
    const float* events = (const float*)d_in[0];
    const float* scat   = (const float*)d_in[1];
    const float* gath   = (const float*)d_in[2];
    const float* wih    = (const float*)d_in[3];
    const float* whh    = (const float*)d_in[4];
    const float* lng    = (const float*)d_in[5];
    const float* lnb    = (const float*)d_in[6];
    const int* posid    = (const int*)d_in[7];
    const int* orig     = (const int*)d_in[8];
    const int* lens     = (const int*)d_in[9];
    char* ws = (char*)d_ws;
    short* evb   = (short*)(ws + OFF_EV);
    short* wcb   = (short*)(ws + OFF_WC);
    short* swb   = (short*)(ws + OFF_SCAT);
    short* gwb   = (short*)(ws + OFF_GATH);
    short* xs    = (short*)(ws + OFF_XS);      // also o_flat (xs dead after lstm)
    short* hs    = (short*)(ws + OFF_HS);
    int*   klist = (int*)(ws + OFF_KLIST);
    int*   eoff  = (int*)(ws + OFF_EOFF);
    int*   ecnt2 = (int*)(ws + OFF_ECNT2);
    int*   tpos  = (int*)(ws + OFF_TPOS);
    int*   seqo  = (int*)(ws + OFF_SEQOFF);
    int*   grp   = (int*)(ws + OFF_GROUP);
    int*   misc  = (int*)(ws + OFF_MISC);
    int*   bh    = (int*)(ws + OFF_BH);
    float* out   = (float*)d_out;

    convhist_kernel<<<NHBLK, 256, 0, stream>>>(events, wih, whh, scat, gath,
                                               evb, wcb, swb, gwb, ecnt2, posid, bh);
    plan_kernel<<<3, 256, 0, stream>>>(bh, misc, lens, seqo, grp, orig, eoff);
    fill_kernel<<<NHBLK, 256, 0, stream>>>(posid, orig, bh, misc, klist, eoff, ecnt2, tpos);
    bucket_gemm<<<NCHUNK_MAX, 256, 0, stream>>>(evb, swb, klist, misc, orig, tpos, xs, 0);
    lstm_kernel<<<256, 512, 0, stream>>>(xs, wcb, hs, seqo, grp, lens);
    bucket_gemm<<<NCHUNK_MAX, 256, 0, stream>>>(hs, gwb, klist, misc, orig, tpos, xs, 1);
    gather_ln<<<4096, 256, 0, stream>>>(xs, eoff, events, lng, lnb, out);
}

// Round 13
// 281.174 us; speedup vs baseline: 1.4682x; 1.4682x over previous
//
#include <hip/hip_runtime.h>

#define N_EVENTS 16384
#define DIM 128
#define NK 9
#define NSEQ 2048
#define TT 147456
#define CHUNK 64
#define NCHUNK_MAX (TT/CHUNK + NK)   // 2313
#define NHBLK 576                    // TT / 256 exactly

typedef __attribute__((ext_vector_type(8))) short bf16x8;
typedef __attribute__((ext_vector_type(4))) float f32x4;
typedef __attribute__((ext_vector_type(4))) int i32x4;
typedef __attribute__((ext_vector_type(2))) int i32x2;

// ---- workspace layout (bytes) ----
#define OFF_EV     0UL                                     // events bf16
#define OFF_WC     (OFF_EV   + (size_t)N_EVENTS*DIM*2)     // [w_ih|w_hh] bf16
#define OFF_SCAT   (OFF_WC   + (size_t)512*256*2)
#define OFF_GATH   (OFF_SCAT + (size_t)NK*DIM*DIM*2)
#define OFF_XS     (OFF_GATH + (size_t)NK*DIM*DIM*2)       // xs bf16; REUSED as o_flat after lstm
#define OFF_HS     (OFF_XS   + (size_t)TT*DIM*2)
#define OFF_KLIST  (OFF_HS   + (size_t)TT*DIM*2)
#define OFF_ECNT   (OFF_KLIST+ (size_t)TT*4)               // event hist: 16384
#define OFF_EOFF   (OFF_ECNT + 16384UL*4)                  // event offsets: 16385
#define OFF_ECNT2  (OFF_EOFF + 16392UL*4)                  // event rank counters
#define OFF_TPOS   (OFF_ECNT2+ 16384UL*4)                  // token -> event-sorted dest: TT
#define OFF_SEQOFF (OFF_TPOS + (size_t)TT*4)
#define OFF_GROUP  (OFF_SEQOFF + (size_t)NSEQ*4)
#define OFF_MISC   (OFF_GROUP  + (size_t)NSEQ*4)
#define OFF_BH     (OFF_MISC   + 256UL)                    // blockhist: 576*9 ints
// misc ints: [0..8]=kcount  [32..40]=koff  [48..57]=choff

__device__ __forceinline__ short f2b(float f) {
    union { float f; unsigned u; } v; v.f = f;
    unsigned r = (v.u + 0x7FFFu + ((v.u >> 16) & 1u)) >> 16;
    return (short)r;
}
__device__ __forceinline__ float asf(unsigned u) {
    union { unsigned u; float f; } v; v.u = u; return v.f;
}
// raw v_rcp_f32 — avoids HIP's ~10-instr IEEE divide (the R8 win)
__device__ __forceinline__ float fsig(float x) {
    return __builtin_amdgcn_rcpf(1.f + __expf(-x));
}
__device__ __forceinline__ float ftanh(float x) {
    return 1.f - 2.f * __builtin_amdgcn_rcpf(__expf(2.f * x) + 1.f);
}

// permlane32_swap selectors (dst<-[a.lo,b.lo], src<-[a.hi,b.hi]):
__device__ __forceinline__ float plo(float a, float b) {
    i32x2 r = __builtin_amdgcn_permlane32_swap(__float_as_int(a), __float_as_int(b),
                                               false, false);
    return __int_as_float(r[0]);
}
__device__ __forceinline__ float phi(float a, float b) {
    i32x2 r = __builtin_amdgcn_permlane32_swap(__float_as_int(a), __float_as_int(b),
                                               false, false);
    return __int_as_float(r[1]);
}

// MFMA with the B operand pinned to AGPR class ("a" constraint).
__device__ __forceinline__ void mfma_vab(f32x4& c, bf16x8 a, bf16x8 b) {
    asm("v_mfma_f32_16x16x32_bf16 %0, %1, %2, %0" : "+v"(c) : "v"(a), "a"(b));
}
#define MFA(c, a, b) mfma_vab(c, a, b);

// Workgroup barrier WITHOUT the vmcnt(0) drain __syncthreads() emits (R7 form).
__device__ __forceinline__ void wg_bar_nodrain() {
    __builtin_amdgcn_sched_barrier(0);
    asm volatile("s_waitcnt lgkmcnt(0)");
    __builtin_amdgcn_s_barrier();
    __builtin_amdgcn_sched_barrier(0);
}

// convert to bf16 + zero the two event-counter arrays
__global__ void convert_kernel(const float* __restrict__ ev, const float* __restrict__ wih,
                               const float* __restrict__ whh, const float* __restrict__ sw,
                               const float* __restrict__ gw,
                               short* __restrict__ evb, short* __restrict__ wcb,
                               short* __restrict__ swb, short* __restrict__ gwb,
                               int* __restrict__ ecnt, int* __restrict__ ecnt2) {
    int idx = blockIdx.x * blockDim.x + threadIdx.x;
    if (idx < N_EVENTS * DIM) evb[idx] = f2b(ev[idx]);
    if (idx < 512 * DIM) {
        int j = idx >> 7, d = idx & 127;
        wcb[j * 256 + d]       = f2b(wih[idx]);
        wcb[j * 256 + 128 + d] = f2b(whh[idx]);
    }
    if (idx < NK * DIM * DIM) { swb[idx] = f2b(sw[idx]); gwb[idx] = f2b(gw[idx]); }
    if (idx < N_EVENTS) { ecnt[idx] = 0; ecnt2[idx] = 0; }
}

// k histogram (LDS) + event histogram (global, ~9-way contention)
__global__ void hist_kernel(const int* __restrict__ pos, const int* __restrict__ orig,
                            int* __restrict__ blockhist, int* __restrict__ ecnt) {
    __shared__ int h[NK];
    int tid = threadIdx.x;
    if (tid < NK) h[tid] = 0;
    __syncthreads();
    int t = blockIdx.x * 256 + tid;
    atomicAdd(&h[pos[t]], 1);
    atomicAdd(&ecnt[orig[t]], 1);
    __syncthreads();
    if (tid < NK) blockhist[blockIdx.x * NK + tid] = h[tid];
}

// 3-role planning kernel: block0 = k-bin scan, block1 = seq setup, block2 = event scan
__global__ void plan_kernel(int* __restrict__ blockhist, int* __restrict__ misc,
                            const int* __restrict__ lengths, int* __restrict__ seq_off,
                            int* __restrict__ grouped,
                            const int* __restrict__ ecnt, int* __restrict__ eoff) {
    int tid = threadIdx.x;
    if (blockIdx.x == 0) {
        __shared__ int h[NHBLK * NK];
        for (int i = tid; i < NHBLK * NK; i += 256) h[i] = blockhist[i];
        __syncthreads();
        if (tid < NK) {
            int run = 0;
            for (int b = 0; b < NHBLK; b++) {
                int v = h[b * NK + tid];
                h[b * NK + tid] = run;
                run += v;
            }
            misc[tid] = run;
        }
        __syncthreads();
        if (tid == 0) {
            int ko = 0, co = 0;
            for (int k = 0; k < NK; k++) {
                int c = misc[k];
                misc[32 + k] = ko;
                misc[48 + k] = co;
                ko += c;
                co += (c + CHUNK - 1) / CHUNK;
            }
            misc[48 + NK] = co;
        }
        __syncthreads();
        for (int i = tid; i < NHBLK * NK; i += 256) blockhist[i] = h[i];
    } else if (blockIdx.x == 1) {
        __shared__ int lens[NSEQ];
        __shared__ int tsum[256], tlong[256];
        for (int i = tid; i < NSEQ; i += 256) lens[i] = lengths[i];
        __syncthreads();
        int base = tid * 8;
        int ls[8]; int s = 0, lc = 0;
        #pragma unroll
        for (int i = 0; i < 8; i++) { ls[i] = lens[base + i]; s += ls[i]; lc += (ls[i] > 64) ? 1 : 0; }
        tsum[tid] = s; tlong[tid] = lc;
        __syncthreads();
        for (int d = 1; d < 256; d <<= 1) {
            int a = (tid >= d) ? tsum[tid - d] : 0;
            int b = (tid >= d) ? tlong[tid - d] : 0;
            __syncthreads();
            tsum[tid] += a; tlong[tid] += b;
            __syncthreads();
        }
        int nlong_total = tlong[255];
        int excl = tsum[tid] - s;
        int excl_long = tlong[tid] - lc;
        int run = 0, runl = 0;
        #pragma unroll
        for (int i = 0; i < 8; i++) {
            int sid = base + i;
            seq_off[sid] = excl + run;
            int lb = excl_long + runl;
            if (ls[i] > 64) { grouped[lb] = sid; runl++; }
            else            { grouped[nlong_total + (sid - lb)] = sid; }
            run += ls[i];
        }
    } else {
        // event scan: 16384 bins, 64 per thread
        __shared__ int part[256];
        int base = tid * 64;
        int s = 0;
        for (int j = 0; j < 64; j++) s += ecnt[base + j];
        part[tid] = s;
        __syncthreads();
        for (int d = 1; d < 256; d <<= 1) {
            int a = (tid >= d) ? part[tid - d] : 0;
            __syncthreads();
            part[tid] += a;
            __syncthreads();
        }
        int run = part[tid] - s;
        for (int j = 0; j < 64; j++) {
            eoff[base + j] = run;
            run += ecnt[base + j];
        }
        if (tid == 255) eoff[N_EVENTS] = run;
    }
}

// scatter tokens to k-sorted klist (LDS rank) + write each token's
// event-sorted destination tokpos[t] = eoff[orig[t]] + rank (replaces elist:
// mode-1 gemm scatters rows to event order so gather_ln reads contiguously).
__global__ void fill_kernel(const int* __restrict__ pos, const int* __restrict__ orig,
                            const int* __restrict__ blockhist, const int* __restrict__ misc,
                            int* __restrict__ klist,
                            const int* __restrict__ eoff, int* __restrict__ ecnt2,
                            int* __restrict__ tokpos) {
    __shared__ int off[NK];
    int tid = threadIdx.x;
    if (tid < NK) off[tid] = misc[32 + tid] + blockhist[blockIdx.x * NK + tid];
    __syncthreads();
    int t = blockIdx.x * 256 + tid;
    int p = atomicAdd(&off[pos[t]], 1);
    klist[p] = t;
    int o = orig[t];
    int p2 = atomicAdd(&ecnt2[o], 1);
    tokpos[t] = eoff[o] + p2;
}

// bucketed position-projection GEMM
// mode 0: A rows = evb[orig[tok]], out rows -> xs[tok]            (bf16)
// mode 1: A rows = hs[tok],        out rows -> o_flat[tokpos[tok]] (bf16)
__global__ void bucket_gemm(const short* __restrict__ src, const short* __restrict__ wall,
                            const int* __restrict__ klist, const int* __restrict__ misc,
                            const int* __restrict__ orig, const int* __restrict__ tokpos,
                            short* __restrict__ rows_out, int mode) {
    const int* chunkoff = misc + 48;
    int b = blockIdx.x;
    if (b >= chunkoff[NK]) return;
    int k = 0;
    while (k < NK - 1 && chunkoff[k + 1] <= b) k++;
    int lc = b - chunkoff[k];
    int cnt = misc[k];
    int base = misc[32 + k] + lc * CHUNK;
    int nv = min(CHUNK, cnt - lc * CHUNK);

    __shared__ int wpos[CHUNK], ridx[CHUNK];
    __shared__ short A[CHUNK * 136];
    int tid = threadIdx.x;
    if (tid < CHUNK) {
        int tv = klist[base + ((tid < nv) ? tid : 0)];
        ridx[tid] = (mode == 0) ? orig[tv] : tv;
        wpos[tid] = (mode == 0) ? tv : tokpos[tv];
    }
    __syncthreads();
    {
        int row = tid >> 2, part = tid & 3;
        const i32x4* s4 = (const i32x4*)(src + (size_t)ridx[row] * DIM + part * 32);
        i32x4* d4 = (i32x4*)(A + row * 136 + part * 32);
        d4[0] = s4[0]; d4[1] = s4[1]; d4[2] = s4[2]; d4[3] = s4[3];
    }
    __syncthreads();
    int wave = tid >> 6, lane = tid & 63, l15 = lane & 15, q = lane >> 4;
    const short* wk = wall + (size_t)k * DIM * DIM;
    bf16x8 Bf[2][4];
    #pragma unroll
    for (int nt = 0; nt < 2; nt++) {
        int h = wave * 32 + nt * 16 + l15;
        #pragma unroll
        for (int kt = 0; kt < 4; kt++)
            Bf[nt][kt] = *(const bf16x8*)(wk + h * DIM + kt * 32 + q * 8);
    }
    f32x4 C[4][2];
    #pragma unroll
    for (int mt = 0; mt < 4; mt++)
        #pragma unroll
        for (int nt = 0; nt < 2; nt++) C[mt][nt] = (f32x4){0.f, 0.f, 0.f, 0.f};
    #pragma unroll
    for (int mt = 0; mt < 4; mt++) {
        bf16x8 Afr[4];
        const short* ar = A + (mt * 16 + l15) * 136 + q * 8;
        Afr[0] = *(const bf16x8*)(ar);
        Afr[1] = *(const bf16x8*)(ar + 32);
        Afr[2] = *(const bf16x8*)(ar + 64);
        Afr[3] = *(const bf16x8*)(ar + 96);
        #pragma unroll
        for (int nt = 0; nt < 2; nt++)
            #pragma unroll
            for (int kt = 0; kt < 4; kt++)
                C[mt][nt] = __builtin_amdgcn_mfma_f32_16x16x32_bf16(Afr[kt], Bf[nt][kt], C[mt][nt], 0, 0, 0);
    }
    __syncthreads();
    #pragma unroll
    for (int mt = 0; mt < 4; mt++)
        #pragma unroll
        for (int nt = 0; nt < 2; nt++)
            #pragma unroll
            for (int r = 0; r < 4; r++) {
                int row = mt * 16 + q * 4 + r;
                int col = wave * 32 + nt * 16 + l15;
                A[row * 136 + col] = f2b(C[mt][nt][r]);
            }
    __syncthreads();
    {
        int row = tid >> 2, part = tid & 3;
        if (row < nv) {
            const i32x4* s4 = (const i32x4*)(A + row * 136 + part * 32);
            i32x4* d4 = (i32x4*)(rows_out + (size_t)wpos[row] * DIM + part * 32);
            d4[0] = s4[0]; d4[1] = s4[1]; d4[2] = s4[2]; d4[3] = s4[3];
        }
    }
}

// ---- 2-step x-batched LSTM group (R7 structure, 120.5 us measured) ----
#define TAIL(IDX, SEL, SLOT) { \
    float iA = SEL(Ci[0], Ci[2]), iB = SEL(Ci[1], Ci[3]); \
    float fA = SEL(Cf[0], Cf[2]), fB = SEL(Cf[1], Cf[3]); \
    float gA = SEL(Cg[0], Cg[2]), gB = SEL(Cg[1], Cg[3]); \
    float oA = SEL(Co[0], Co[2]), oB = SEL(Co[1], Co[3]); \
    if ((IDX) < lenA) { \
        float si = fsig(iA), sf = fsig(fA), so = fsig(oA); \
        float tg = ftanh(gA); \
        float cn = sf * cA + si * tg; \
        float th = ftanh(cn); \
        cA = cn; \
        hb[(SLOT) * 1088 + rowA * 136 + u] = f2b(so * th); \
    } \
    if ((IDX) < lenB) { \
        float si = fsig(iB), sf = fsig(fB), so = fsig(oB); \
        float tg = ftanh(gB); \
        float cn = sf * cB + si * tg; \
        float th = ftanh(cn); \
        cB = cn; \
        hb[(SLOT) * 1088 + rowB * 136 + u] = f2b(so * th); \
    } \
}

#define LSTM_G(J2, PF) { \
    const int i2 = ib8 + 2 * (J2); \
    f32x4 Ci = {0.f,0.f,0.f,0.f}, Cf = {0.f,0.f,0.f,0.f}; \
    f32x4 Cg = {0.f,0.f,0.f,0.f}, Co = {0.f,0.f,0.f,0.f}; \
    MFA(Ci, PF[0], Bf[0][0]) MFA(Cf, PF[0], Bf[1][0]) \
    MFA(Cg, PF[0], Bf[2][0]) MFA(Co, PF[0], Bf[3][0]) \
    MFA(Ci, PF[1], Bf[0][1]) MFA(Cf, PF[1], Bf[1][1]) \
    MFA(Cg, PF[1], Bf[2][1]) MFA(Co, PF[1], Bf[3][1]) \
    MFA(Ci, PF[2], Bf[0][2]) MFA(Cf, PF[2], Bf[1][2]) \
    MFA(Cg, PF[2], Bf[2][2]) MFA(Co, PF[2], Bf[3][2]) \
    MFA(Ci, PF[3], Bf[0][3]) MFA(Cf, PF[3], Bf[1][3]) \
    MFA(Cg, PF[3], Bf[2][3]) MFA(Co, PF[3], Bf[3][3]) \
    bf16x8 He0, He1, He2, He3; \
    { const short* hp_ = b0 + (lo8 ? (((2*(J2)+7)&7) * 1088) : 8704); \
      He0 = *(const bf16x8*)(hp_);      He1 = *(const bf16x8*)(hp_ + 32); \
      He2 = *(const bf16x8*)(hp_ + 64); He3 = *(const bf16x8*)(hp_ + 96); } \
    MFA(Ci, He0, Bf[0][4]) MFA(Cf, He0, Bf[1][4]) \
    MFA(Cg, He0, Bf[2][4]) MFA(Co, He0, Bf[3][4]) \
    MFA(Ci, He1, Bf[0][5]) MFA(Cf, He1, Bf[1][5]) \
    MFA(Cg, He1, Bf[2][5]) MFA(Co, He1, Bf[3][5]) \
    MFA(Ci, He2, Bf[0][6]) MFA(Cf, He2, Bf[1][6]) \
    MFA(Cg, He2, Bf[2][6]) MFA(Co, He2, Bf[3][6]) \
    MFA(Ci, He3, Bf[0][7]) MFA(Cf, He3, Bf[1][7]) \
    MFA(Cg, He3, Bf[2][7]) MFA(Co, He3, Bf[3][7]) \
    TAIL(i2, plo, (2*(J2)) & 7) \
    wg_bar_nodrain(); \
    bf16x8 Ho0, Ho1, Ho2, Ho3; \
    { const short* hp_ = b0 + (lo8 ? 8704 : (((2*(J2)) & 7) * 1088)); \
      Ho0 = *(const bf16x8*)(hp_);      Ho1 = *(const bf16x8*)(hp_ + 32); \
      Ho2 = *(const bf16x8*)(hp_ + 64); Ho3 = *(const bf16x8*)(hp_ + 96); } \
    MFA(Ci, Ho0, Bf[0][4]) MFA(Cf, Ho0, Bf[1][4]) \
    MFA(Cg, Ho0, Bf[2][4]) MFA(Co, Ho0, Bf[3][4]) \
    MFA(Ci, Ho1, Bf[0][5]) MFA(Cf, Ho1, Bf[1][5]) \
    MFA(Cg, Ho1, Bf[2][5]) MFA(Co, Ho1, Bf[3][5]) \
    MFA(Ci, Ho2, Bf[0][6]) MFA(Cf, Ho2, Bf[1][6]) \
    MFA(Cg, Ho2, Bf[2][6]) MFA(Co, Ho2, Bf[3][6]) \
    MFA(Ci, Ho3, Bf[0][7]) MFA(Cf, Ho3, Bf[1][7]) \
    MFA(Cg, Ho3, Bf[2][7]) MFA(Co, Ho3, Bf[3][7]) \
    { const short* xp_ = xs + xoff; \
      PF[0] = *(const bf16x8*)(xp_);      PF[1] = *(const bf16x8*)(xp_ + 32); \
      PF[2] = *(const bf16x8*)(xp_ + 64); PF[3] = *(const bf16x8*)(xp_ + 96); } \
    xoff += ((i2 + 6 + loff) < my_len) ? 2 * DIM : 0; \
    TAIL(i2 + 1, phi, (2*(J2)+1) & 7) \
    wg_bar_nodrain(); \
}

// Persistent per-sequence LSTM — 2-step x-batched (R7/R9, 120.5 us).
__global__ __launch_bounds__(512)
__attribute__((amdgpu_waves_per_eu(2, 2)))
void lstm_kernel(
        const short* __restrict__ xs, const short* __restrict__ wc,
        short* __restrict__ hstore, const int* __restrict__ seq_off,
        const int* __restrict__ grouped, const int* __restrict__ lengths) {
    __shared__ int s_off[8], s_len[8];
    __shared__ short hchunk[11][8][136];   // slots 0-7 = h ring; slot 8 = always-zero
    int tid = threadIdx.x;
    if (tid < 8) {
        int s = grouped[blockIdx.x * 8 + tid];
        s_off[tid] = seq_off[s];
        s_len[tid] = lengths[s];
    }
    for (int j = tid; j < 11 * 8 * 136; j += 512) ((short*)hchunk)[j] = 0;
    __syncthreads();
    int lane = tid & 63, l15 = lane & 15, ql = lane >> 4;
    int wave = tid >> 6;
    int u = wave * 16 + l15;
    short* hb = (short*)hchunk;
    bf16x8 Bf[4][8];
    #pragma unroll
    for (int g = 0; g < 4; g++) {
        int j = g * 128 + u;
        #pragma unroll
        for (int kt = 0; kt < 8; kt++)
            Bf[g][kt] = *(const bf16x8*)(wc + j * 256 + kt * 32 + ql * 8);
    }
    int maxlen = 0;
    #pragma unroll
    for (int i = 0; i < 8; i++) maxlen = max(maxlen, s_len[i]);
    int sq = l15 & 7;
    int loff = l15 >> 3;             // 0 = even-step row, 1 = odd-step row
    bool lo8 = (l15 < 8);
    int my_off = s_off[sq];
    int my_len = s_len[sq];
    const short* b0 = hb + sq * 136 + ql * 8;   // + slot*1088 selects ring slot
    int rowA = (ql < 2) ? (ql * 4 + 0) : ((ql - 2) * 4 + 2);
    int rowB = (ql < 2) ? (ql * 4 + 1) : ((ql - 2) * 4 + 3);
    int lenA = s_len[rowA], lenB = s_len[rowB];
    float cA = 0.f, cB = 0.f;
    // prime: Pf0 = steps {0,1}, Pf1 = steps {2,3} (all 16 A-rows loaded)
    bf16x8 Pf0[4], Pf1[4];
    int xoff = (my_off + loff) * DIM + ql * 8;
    {
        const short* xp = xs + xoff;
        Pf0[0] = *(const bf16x8*)(xp);      Pf0[1] = *(const bf16x8*)(xp + 32);
        Pf0[2] = *(const bf16x8*)(xp + 64); Pf0[3] = *(const bf16x8*)(xp + 96);
        const short* xq = xp + 2 * DIM;
        Pf1[0] = *(const bf16x8*)(xq);      Pf1[1] = *(const bf16x8*)(xq + 32);
        Pf1[2] = *(const bf16x8*)(xq + 64); Pf1[3] = *(const bf16x8*)(xq + 96);
    }
    xoff += 4 * DIM;   // first refill target = steps {4,5} (valid: len >= 36)

    int nb8 = (maxlen + 7) >> 3;
    for (int ob = 0; ob < nb8; ob++) {
        int ib8 = ob * 8;
        LSTM_G(0, Pf0)
        LSTM_G(1, Pf1)
        LSTM_G(2, Pf0)
        LSTM_G(3, Pf1)
        #pragma unroll
        for (int it = 0; it < 2; it++) {
            int idx = tid + it * 512;
            int st = idx >> 7, s = (idx >> 4) & 7, part = idx & 15;
            int ig = ib8 + st;
            if (ig < s_len[s]) {
                i32x4 v = *(const i32x4*)&hchunk[st][s][part * 8];
                *(i32x4*)(hstore + (size_t)(s_off[s] + ig) * DIM + part * 8) = v;
            }
        }
        wg_bar_nodrain();
    }
}

// gather each event's rows — CONTIGUOUS [eoff[e], eoff[e+1]) (R9 layout).
__global__ void gather_ln(const short* __restrict__ of, const int* __restrict__ eoff,
                          const float* __restrict__ ev,
                          const float* __restrict__ g, const float* __restrict__ bta,
                          float* __restrict__ out) {
    int tid = threadIdx.x;
    int wave = tid >> 6, lane = tid & 63;
    int e = blockIdx.x * 4 + wave;
    int s0 = eoff[e], s1 = eoff[e + 1];
    float x0 = 0.f, x1 = 0.f;
    for (int j = s0; j < s1; j++) {
        unsigned v = *(const unsigned*)(of + (size_t)j * DIM + lane * 2);
        x0 += asf(v << 16);
        x1 += asf(v & 0xffff0000u);
    }
    const float2* e2 = (const float2*)(ev + (size_t)e * DIM);
    float2 evv = e2[lane];
    x0 += evv.x; x1 += evv.y;
    float sm = x0 + x1, sq = x0 * x0 + x1 * x1;
    #pragma unroll
    for (int m = 1; m < 64; m <<= 1) {
        sm += __shfl_xor(sm, m, 64);
        sq += __shfl_xor(sq, m, 64);
    }
    float mean = sm * (1.f / DIM);
    float var = sq * (1.f / DIM) - mean * mean;
    float rs = rsqrtf(var + 1e-5f);
    float2 gv = ((const float2*)g)[lane], bv = ((const float2*)bta)[lane];
    float2 ov;
    ov.x = (x0 - mean) * rs * gv.x + bv.x;
    ov.y = (x1 - mean) * rs * gv.y + bv.y;
    ((float2*)(out + (size_t)e * DIM))[lane] = ov;
}

extern "C" void kernel_launch(void* const* d_in, const int* in_sizes, int n_in,
                              void* d_out, int out_size, void* d_ws, size_t ws_size,
                              hipStream_t stream) {
    const float* events = (const float*)d_in[0];
    const float* scat   = (const float*)d_in[1];
    const float* gath   = (const float*)d_in[2];
    const float* wih    = (const float*)d_in[3];
    const float* whh    = (const float*)d_in[4];
    const float* lng    = (const float*)d_in[5];
    const float* lnb    = (const float*)d_in[6];
    const int* posid    = (const int*)d_in[7];
    const int* orig     = (const int*)d_in[8];
    const int* lens     = (const int*)d_in[9];
    char* ws = (char*)d_ws;
    short* evb   = (short*)(ws + OFF_EV);
    short* wcb   = (short*)(ws + OFF_WC);
    short* swb   = (short*)(ws + OFF_SCAT);
    short* gwb   = (short*)(ws + OFF_GATH);
    short* xs    = (short*)(ws + OFF_XS);      // also o_flat (xs dead after lstm)
    short* hs    = (short*)(ws + OFF_HS);
    int*   klist = (int*)(ws + OFF_KLIST);
    int*   ecnt  = (int*)(ws + OFF_ECNT);
    int*   eoff  = (int*)(ws + OFF_EOFF);
    int*   ecnt2 = (int*)(ws + OFF_ECNT2);
    int*   tpos  = (int*)(ws + OFF_TPOS);
    int*   seqo  = (int*)(ws + OFF_SEQOFF);
    int*   grp   = (int*)(ws + OFF_GROUP);
    int*   misc  = (int*)(ws + OFF_MISC);
    int*   bh    = (int*)(ws + OFF_BH);
    float* out   = (float*)d_out;

    convert_kernel<<<8192, 256, 0, stream>>>(events, wih, whh, scat, gath,
                                             evb, wcb, swb, gwb, ecnt, ecnt2);
    hist_kernel<<<NHBLK, 256, 0, stream>>>(posid, orig, bh, ecnt);
    plan_kernel<<<3, 256, 0, stream>>>(bh, misc, lens, seqo, grp, ecnt, eoff);
    fill_kernel<<<NHBLK, 256, 0, stream>>>(posid, orig, bh, misc, klist, eoff, ecnt2, tpos);
    bucket_gemm<<<NCHUNK_MAX, 256, 0, stream>>>(evb, swb, klist, misc, orig, tpos, xs, 0);
    lstm_kernel<<<256, 512, 0, stream>>>(xs, wcb, hs, seqo, grp, lens);
    bucket_gemm<<<NCHUNK_MAX, 256, 0, stream>>>(hs, gwb, klist, misc, orig, tpos, xs, 1);
    gather_ln<<<4096, 256, 0, stream>>>(xs, eoff, events, lng, lnb, out);
}